// Round 4
// baseline (528.094 us; speedup 1.0000x reference)
//
#include <hip/hip_runtime.h>
#include <stdint.h>
#include <stddef.h>

#define B_ 8
#define D_ 128
#define T_ 32768
#define C_ 64

typedef __bf16 bf16;
typedef __bf16 bf16x8 __attribute__((ext_vector_type(8)));
typedef float f32x4 __attribute__((ext_vector_type(4)));
typedef float f32x16 __attribute__((ext_vector_type(16)));

__device__ __forceinline__ f32x16 zero16() {
  f32x16 z;
#pragma unroll
  for (int i = 0; i < 16; ++i) z[i] = 0.f;
  return z;
}
__device__ __forceinline__ bf16x8 cvt8(f32x4 lo, f32x4 hi) {
  bf16x8 r;
#pragma unroll
  for (int j = 0; j < 4; ++j) { r[j] = (bf16)lo[j]; r[j + 4] = (bf16)hi[j]; }
  return r;
}
__device__ __forceinline__ void load_lds16(const bf16* g, bf16* l) {
  __builtin_amdgcn_global_load_lds(
      (const __attribute__((address_space(1))) void*)g,
      (__attribute__((address_space(3))) void*)l, 16, 0, 0);
}

// ---------------------------------------------------------------------------
// K0: zero G[b][128][128] and r[b][128] (only needed on the atomic path)
// ---------------------------------------------------------------------------
__global__ __launch_bounds__(256) void k0_zero(float* __restrict__ p, int n)
{
  int i = blockIdx.x * 256 + threadIdx.x;
  if (i < n) p[i] = 0.f;
}

// ---------------------------------------------------------------------------
// K1: per-(batch, t-chunk) Gram partial of x1 x1^T; either plain-stored to Gp
//     (reduced by K2) or atomicAdd'ed into G. Optionally writes bf16 copy of
//     x1 (x_bf) for K4. 64 extra blocks fold weights wk'=we@wk, wv'=wf@wv.
// ---------------------------------------------------------------------------
__global__ __launch_bounds__(256) void k1_gram(
    const float* __restrict__ x1,
    const float* __restrict__ we, const float* __restrict__ wk,
    const float* __restrict__ bk, const float* __restrict__ be,
    const float* __restrict__ wf, const float* __restrict__ wv,
    const float* __restrict__ bv, const float* __restrict__ bfv,
    float* __restrict__ G, float* __restrict__ r,
    float* __restrict__ Gp, float* __restrict__ rp,
    float* __restrict__ wkp, float* __restrict__ wvp,
    float* __restrict__ bkp, float* __restrict__ bvp,
    bf16* __restrict__ xbf,
    int nchunk, int use_atomic, int use_xbf)
{
  const int blk = blockIdx.x;
  const int tid = threadIdx.x;
  const int ngram = B_ * nchunk;

  if (blk >= ngram) {
    const int wb = blk - ngram;
    const float* wa  = (wb < 32) ? we : wf;
    const float* wb2 = (wb < 32) ? wk : wv;
    float* outw      = (wb < 32) ? wkp : wvp;
    const int idx = (wb & 31) * 256 + tid;   // 0..8191
    const int o = idx >> 7, d = idx & 127;
    float s = 0.f;
    for (int c = 0; c < 64; ++c) s += wa[o * 64 + c] * wb2[c * 128 + d];
    outw[idx] = s;
    if (tid < 64) {
      if (wb == 0) {
        float t = 0.f;
        for (int c = 0; c < 64; ++c) t += we[tid * 64 + c] * bk[c];
        bkp[tid] = t + be[tid];
      } else if (wb == 32) {
        float t = 0.f;
        for (int c = 0; c < 64; ++c) t += wf[tid * 64 + c] * bv[c];
        bvp[tid] = t + bfv[tid];
      }
    }
    return;
  }

  const int b  = blk / nchunk;
  const int ch = blk % nchunk;
  const int Tc = T_ / nchunk;
  const int t0 = ch * Tc;
  const int wave = tid >> 6, lane = tid & 63;
  const int lrow = lane & 31, lk = lane >> 5;
  const int qa = wave >> 1, qb = wave & 1;   // wave owns 64x64 quadrant (64qa, 64qb)

  const float* xb = x1 + (size_t)b * D_ * T_;
  const float* pa0 = xb + (size_t)(64 * qa + lrow) * T_ + 8 * lk;
  const float* pa1 = pa0 + (size_t)32 * T_;
  const float* pb0 = xb + (size_t)(64 * qb + lrow) * T_ + 8 * lk;
  const float* pb1 = pb0 + (size_t)32 * T_;
  bf16* xo = use_xbf ? (xbf + (size_t)b * D_ * T_ + (size_t)(64 * qa + lrow) * T_ + 8 * lk)
                     : (bf16*)nullptr;

  f32x16 acc00 = zero16(), acc01 = zero16(), acc10 = zero16(), acc11 = zero16();
  float rsum = 0.f;

  for (int t = t0; t < t0 + Tc; t += 16) {
    f32x4 a0l = *(const f32x4*)(pa0 + t), a0h = *(const f32x4*)(pa0 + t + 4);
    f32x4 a1l = *(const f32x4*)(pa1 + t), a1h = *(const f32x4*)(pa1 + t + 4);
    f32x4 b0l = *(const f32x4*)(pb0 + t), b0h = *(const f32x4*)(pb0 + t + 4);
    f32x4 b1l = *(const f32x4*)(pb1 + t), b1h = *(const f32x4*)(pb1 + t + 4);
    bf16x8 fa0 = cvt8(a0l, a0h);
    bf16x8 fa1 = cvt8(a1l, a1h);
    bf16x8 fb0 = cvt8(b0l, b0h);
    bf16x8 fb1 = cvt8(b1l, b1h);
    if (use_xbf && qb == 0) {          // each row stored exactly once (waves 0,2)
      *(bf16x8*)(xo + t) = fa0;
      *(bf16x8*)(xo + (size_t)32 * T_ + t) = fa1;
    }
    // row-sum duty: wave w=2qa+qb covers d-rows 32w..32w+31 (fp32-exact)
    f32x4 ol = qb ? a1l : a0l, oh = qb ? a1h : a0h;
#pragma unroll
    for (int j = 0; j < 4; ++j) rsum += ol[j] + oh[j];
    acc00 = __builtin_amdgcn_mfma_f32_32x32x16_bf16(fa0, fb0, acc00, 0, 0, 0);
    acc01 = __builtin_amdgcn_mfma_f32_32x32x16_bf16(fa0, fb1, acc01, 0, 0, 0);
    acc10 = __builtin_amdgcn_mfma_f32_32x32x16_bf16(fa1, fb0, acc10, 0, 0, 0);
    acc11 = __builtin_amdgcn_mfma_f32_32x32x16_bf16(fa1, fb1, acc11, 0, 0, 0);
  }

  float rtot = rsum + __shfl_xor(rsum, 32, 64);

  if (use_atomic) {
    float* gb = G + (size_t)b * 16384;
#pragma unroll
    for (int rr = 0; rr < 16; ++rr) {
      const int rloc = (rr & 3) + 8 * (rr >> 2) + 4 * lk;   // C/D row map (m74/m101)
      const int r0 = 64 * qa + rloc, r1 = 64 * qa + 32 + rloc;
      const int c0 = 64 * qb + lrow, c1 = 64 * qb + 32 + lrow;
      atomicAdd(&gb[r0 * 128 + c0], acc00[rr]);
      atomicAdd(&gb[r0 * 128 + c1], acc01[rr]);
      atomicAdd(&gb[r1 * 128 + c0], acc10[rr]);
      atomicAdd(&gb[r1 * 128 + c1], acc11[rr]);
    }
    if (lk == 0) atomicAdd(&r[b * 128 + 32 * wave + lrow], rtot);
  } else {
    float* gb = Gp + (size_t)(b * nchunk + ch) * 16384;
#pragma unroll
    for (int rr = 0; rr < 16; ++rr) {
      const int rloc = (rr & 3) + 8 * (rr >> 2) + 4 * lk;
      const int r0 = 64 * qa + rloc, r1 = 64 * qa + 32 + rloc;
      const int c0 = 64 * qb + lrow, c1 = 64 * qb + 32 + lrow;
      gb[r0 * 128 + c0] = acc00[rr];
      gb[r0 * 128 + c1] = acc01[rr];
      gb[r1 * 128 + c0] = acc10[rr];
      gb[r1 * 128 + c1] = acc11[rr];
    }
    if (lk == 0) rp[(size_t)(b * nchunk + ch) * 128 + 32 * wave + lrow] = rtot;
  }
}

// ---------------------------------------------------------------------------
// K2: reduce chunk partials -> G[b][128][128], r[b][128] (partial path only)
// ---------------------------------------------------------------------------
__global__ __launch_bounds__(256) void k2_reduce(
    const float* __restrict__ Gp, const float* __restrict__ rp,
    float* __restrict__ G, float* __restrict__ r, int nchunk)
{
  const int b = blockIdx.x >> 4, part = blockIdx.x & 15;
  const int tid = threadIdx.x;
  const float* gpb = Gp + (size_t)b * nchunk * 16384;
#pragma unroll
  for (int q = 0; q < 4; ++q) {
    const int idx = part * 1024 + q * 256 + tid;
    float s = 0.f;
    for (int ch = 0; ch < nchunk; ++ch) s += gpb[(size_t)ch * 16384 + idx];
    G[(size_t)b * 16384 + idx] = s;
  }
  if (part == 0 && tid < 128) {
    const float* rpb = rp + (size_t)b * nchunk * 128;
    float s = 0.f;
    for (int ch = 0; ch < nchunk; ++ch) s += rpb[ch * 128 + tid];
    r[b * 128 + tid] = s;
  }
}

// ---------------------------------------------------------------------------
// K3: per (b, c): S[c,:] = wq_c G wk'^T + exact bias terms (via r),
//     P = softmax(S/8), att_w[c,:] = P @ wv' (bf16), att_b[c] = P @ bv'
// ---------------------------------------------------------------------------
__global__ __launch_bounds__(128) void k3_softmax(
    const float* __restrict__ wq, const float* __restrict__ bq,
    const float* __restrict__ G, const float* __restrict__ r,
    const float* __restrict__ wkp, const float* __restrict__ wvp,
    const float* __restrict__ bkp, const float* __restrict__ bvp,
    bf16* __restrict__ attw, float* __restrict__ attb)
{
  const int b = blockIdx.x >> 6, c = blockIdx.x & 63;
  const int tid = threadIdx.x;
  __shared__ float sM[128], sR[128], sQ[128], sP[64];
  __shared__ float sRed;

  const float* Gb = G + (size_t)b * 16384;
  const float* wqc = wq + c * 128;

  const float rv = r[b * 128 + tid];
  sR[tid] = rv;
  float m = 0.f;
  for (int j = 0; j < 128; ++j) m += wqc[j] * Gb[j * 128 + tid];
  sM[tid] = m;
  sQ[tid] = wqc[tid] * rv;
  __syncthreads();

  if (tid < 64) {
    float q2 = sQ[tid] + sQ[tid + 64];
#pragma unroll
    for (int off = 32; off; off >>= 1) q2 += __shfl_xor(q2, off, 64);
    if (tid == 0) sRed = q2;
  }
  __syncthreads();
  const float qr = sRed;
  const float bqc = bq[c];

  if (tid < 64) {
    const int k = tid;
    float s = 0.f, wkr = 0.f;
    for (int i = 0; i < 128; ++i) {
      const float w = wkp[k * 128 + i];
      s += sM[i] * w;
      wkr += sR[i] * w;
    }
    const float bk2 = bkp[k];
    float logit = (s + bqc * wkr + bk2 * qr + (float)T_ * bqc * bk2) * 0.125f;
    float mx = logit;
#pragma unroll
    for (int off = 32; off; off >>= 1) mx = fmaxf(mx, __shfl_xor(mx, off, 64));
    const float e = __expf(logit - mx);
    float sum = e;
#pragma unroll
    for (int off = 32; off; off >>= 1) sum += __shfl_xor(sum, off, 64);
    sP[k] = e / sum;
  }
  __syncthreads();

  {
    float aw = 0.f;
    for (int k = 0; k < 64; ++k) aw += sP[k] * wvp[k * 128 + tid];
    attw[((size_t)b * 64 + c) * 128 + tid] = (bf16)aw;
  }
  if (tid < 64) {
    float pb = sP[tid] * bvp[tid];
#pragma unroll
    for (int off = 32; off; off >>= 1) pb += __shfl_xor(pb, off, 64);
    if (tid == 0) attb[b * 64 + c] = pb;
  }
}

// ---------------------------------------------------------------------------
// K4: fused output, one 128x128 (d x t) tile per block.
//   x staged into LDS [d][t] (global_load_lds from x_bf when available, else
//   fp32+cvt). Stage1 m1 = relu(attw@x + ab) written into rows 64..127 of
//   x_lds (per-wave column ownership -> no barrier). Stage2 out = wo@m1+bo,
//   masked fp32 store. Single barrier per tile; LDS ~33KB -> 4 blocks/CU.
// ---------------------------------------------------------------------------
__global__ __launch_bounds__(256, 4) void k4_out(
    const float* __restrict__ x1, const bf16* __restrict__ xbf,
    const float* __restrict__ mask,
    const float* __restrict__ wo, const float* __restrict__ bo,
    const bf16* __restrict__ attw, const float* __restrict__ attb,
    float* __restrict__ out, int use_xbf)
{
  __shared__ bf16 x_lds[128 * 128];   // rows 0..127 = x; rows 64..127 reused for m1
  __shared__ float bo_lds[128];
  __shared__ float ab_lds[64];
  bf16* m1_lds = &x_lds[64 * 128];

  const int b = blockIdx.x >> 8;        // T_/128 = 256 tiles per batch
  const int t0 = (blockIdx.x & 255) * 128;
  const int tid = threadIdx.x;
  const int wave = tid >> 6, lane = tid & 63;
  const int lrow = lane & 31, lk = lane >> 5;

  if (use_xbf) {
    const bf16* xbb = xbf + (size_t)b * D_ * T_ + t0;
#pragma unroll
    for (int i = 0; i < 8; ++i) {
      const int d0 = 32 * wave + 4 * i;                       // wave-uniform
      const bf16* src = xbb + (size_t)(d0 + (lane >> 4)) * T_ + (lane & 15) * 8;
      load_lds16(src, &x_lds[d0 * 128]);                      // lane L -> base+16L
    }
  } else {
    const float* xb = x1 + (size_t)b * D_ * T_;
    const int dr = tid >> 4;            // 0..15
    const int tc = (tid & 15) * 8;
#pragma unroll
    for (int it = 0; it < 8; ++it) {
      const int d = it * 16 + dr;
      f32x4 lo = *(const f32x4*)(xb + (size_t)d * T_ + t0 + tc);
      f32x4 hi = *(const f32x4*)(xb + (size_t)d * T_ + t0 + tc + 4);
      *(bf16x8*)&x_lds[d * 128 + tc] = cvt8(lo, hi);
    }
  }
  if (tid < 128) bo_lds[tid] = bo[tid];
  if (tid < 64) ab_lds[tid] = attb[b * 64 + tid];
  __syncthreads();

  const int tcol = 32 * wave + lrow;

  // ---- stage 1: M1[c][t] = att_w[c][d] * x[d][t], c in 0..63
  f32x16 p0 = zero16(), p1 = zero16();
  const bf16* awb = attw + (size_t)b * 64 * 128;
#pragma unroll
  for (int k0 = 0; k0 < 128; k0 += 16) {
    bf16x8 a0 = *(const bf16x8*)(awb + (size_t)(lrow) * 128 + k0 + 8 * lk);
    bf16x8 a1 = *(const bf16x8*)(awb + (size_t)(32 + lrow) * 128 + k0 + 8 * lk);
    bf16x8 bx;
#pragma unroll
    for (int j = 0; j < 8; ++j) bx[j] = x_lds[(k0 + 8 * lk + j) * 128 + tcol];
    p0 = __builtin_amdgcn_mfma_f32_32x32x16_bf16(a0, bx, p0, 0, 0, 0);
    p1 = __builtin_amdgcn_mfma_f32_32x32x16_bf16(a1, bx, p1, 0, 0, 0);
  }
  // write m1 into rows 64..127 of x_lds — own columns only, x rows 64..127
  // already consumed by this wave; other waves never touch our columns.
#pragma unroll
  for (int rr = 0; rr < 16; ++rr) {
    const int row = (rr & 3) + 8 * (rr >> 2) + 4 * lk;
    m1_lds[row * 128 + tcol]        = (bf16)fmaxf(p0[rr] + ab_lds[row], 0.f);
    m1_lds[(32 + row) * 128 + tcol] = (bf16)fmaxf(p1[rr] + ab_lds[32 + row], 0.f);
  }

  // ---- stage 2: out[d][t] = wo[d][c] * m1[c][t] (own columns, no barrier)
  f32x16 q0 = zero16(), q1 = zero16(), q2 = zero16(), q3 = zero16();
#pragma unroll
  for (int k0 = 0; k0 < 64; k0 += 16) {
    bf16x8 bm;
#pragma unroll
    for (int j = 0; j < 8; ++j) bm[j] = m1_lds[(k0 + 8 * lk + j) * 128 + tcol];
#pragma unroll
    for (int i = 0; i < 4; ++i) {
      const float* wrow = wo + (size_t)(32 * i + lrow) * 64 + k0 + 8 * lk;
      bf16x8 wfrag = cvt8(*(const f32x4*)wrow, *(const f32x4*)(wrow + 4));
      if (i == 0) q0 = __builtin_amdgcn_mfma_f32_32x32x16_bf16(wfrag, bm, q0, 0, 0, 0);
      if (i == 1) q1 = __builtin_amdgcn_mfma_f32_32x32x16_bf16(wfrag, bm, q1, 0, 0, 0);
      if (i == 2) q2 = __builtin_amdgcn_mfma_f32_32x32x16_bf16(wfrag, bm, q2, 0, 0, 0);
      if (i == 3) q3 = __builtin_amdgcn_mfma_f32_32x32x16_bf16(wfrag, bm, q3, 0, 0, 0);
    }
  }

  const float mv = mask[(size_t)b * T_ + t0 + tcol];
  float* ob = out + (size_t)b * D_ * T_ + t0 + tcol;
#pragma unroll
  for (int rr = 0; rr < 16; ++rr) {
    const int row = (rr & 3) + 8 * (rr >> 2) + 4 * lk;
    ob[(size_t)(row) * T_]      = (q0[rr] + bo_lds[row]) * mv;
    ob[(size_t)(32 + row) * T_] = (q1[rr] + bo_lds[32 + row]) * mv;
    ob[(size_t)(64 + row) * T_] = (q2[rr] + bo_lds[64 + row]) * mv;
    ob[(size_t)(96 + row) * T_] = (q3[rr] + bo_lds[96 + row]) * mv;
  }
}

// ---------------------------------------------------------------------------
extern "C" void kernel_launch(void* const* d_in, const int* in_sizes, int n_in,
                              void* d_out, int out_size, void* d_ws, size_t ws_size,
                              hipStream_t stream)
{
  const float* x1   = (const float*)d_in[0];
  // d_in[1] = x2 (unused in encoder stage)
  const float* mask = (const float*)d_in[2];
  const float* wq   = (const float*)d_in[3];
  const float* bq   = (const float*)d_in[4];
  const float* wk   = (const float*)d_in[5];
  const float* bk   = (const float*)d_in[6];
  const float* wv   = (const float*)d_in[7];
  const float* bv   = (const float*)d_in[8];
  const float* we   = (const float*)d_in[9];
  const float* be   = (const float*)d_in[10];
  const float* wf   = (const float*)d_in[11];
  const float* bfv  = (const float*)d_in[12];
  const float* wo   = (const float*)d_in[13];
  const float* bo   = (const float*)d_in[14];
  float* out = (float*)d_out;

  // fixed region
  char* base = (char*)d_ws;
  size_t off = 0;
  float* G   = (float*)(base + off); off += (size_t)B_ * 16384 * 4;
  float* r   = (float*)(base + off); off += (size_t)B_ * 128 * 4;
  float* wkp = (float*)(base + off); off += 8192 * 4;
  float* wvp = (float*)(base + off); off += 8192 * 4;
  float* bkp = (float*)(base + off); off += 64 * 4;
  float* bvp = (float*)(base + off); off += 64 * 4;
  float* attb = (float*)(base + off); off += (size_t)B_ * 64 * 4;
  bf16* attw = (bf16*)(base + off); off += (size_t)B_ * 64 * 128 * 2;
  off = (off + 255) & ~(size_t)255;
  const size_t fixed_end = off;

  const size_t xbf_bytes = (size_t)B_ * D_ * T_ * 2;          // 67.1 MB
  auto gp_bytes = [](int nc) {
    return (size_t)B_ * nc * 16384 * 4 + (size_t)B_ * nc * 128 * 4;
  };

  int nchunk, use_atomic, use_xbf;
  size_t gp_off;
  if (ws_size >= fixed_end + xbf_bytes + gp_bytes(64)) {
    use_xbf = 1; use_atomic = 0; nchunk = 64; gp_off = fixed_end + xbf_bytes;
  } else if (ws_size >= fixed_end + xbf_bytes) {
    use_xbf = 1; use_atomic = 1; nchunk = 32; gp_off = fixed_end;
  } else if (ws_size >= fixed_end + gp_bytes(32)) {
    use_xbf = 0; use_atomic = 0; nchunk = 32; gp_off = fixed_end;
  } else {
    use_xbf = 0; use_atomic = 1; nchunk = 32; gp_off = fixed_end;
  }
  bf16* xbf = (bf16*)(base + fixed_end);
  float* Gp = (float*)(base + gp_off);
  float* rp = Gp + (size_t)B_ * nchunk * 16384;

  if (use_atomic) {
    const int nzero = B_ * 16384 + B_ * 128;   // G + r contiguous
    k0_zero<<<(nzero + 255) / 256, 256, 0, stream>>>(G, nzero);
  }
  k1_gram<<<B_ * nchunk + 64, 256, 0, stream>>>(
      x1, we, wk, bk, be, wf, wv, bv, bfv,
      G, r, Gp, rp, wkp, wvp, bkp, bvp, xbf, nchunk, use_atomic, use_xbf);
  if (!use_atomic)
    k2_reduce<<<B_ * 16, 256, 0, stream>>>(Gp, rp, G, r, nchunk);
  k3_softmax<<<B_ * 64, 128, 0, stream>>>(wq, bq, G, r, wkp, wvp, bkp, bvp, attw, attb);
  k4_out<<<B_ * (T_ / 128), 256, 0, stream>>>(x1, xbf, mask, wo, bo, attw, attb, out,
                                              use_xbf);
}

// Round 5
// 416.080 us; speedup vs baseline: 1.2692x; 1.2692x over previous
//
#include <hip/hip_runtime.h>
#include <stdint.h>
#include <stddef.h>

#define B_ 8
#define D_ 128
#define T_ 32768
#define C_ 64
#define NCH_ 128      // t-chunks per batch in k1; Tc = 256

typedef __bf16 bf16;
typedef __bf16 bf16x4 __attribute__((ext_vector_type(4)));
typedef __bf16 bf16x8 __attribute__((ext_vector_type(8)));
typedef float f32x4 __attribute__((ext_vector_type(4)));
typedef float f32x16 __attribute__((ext_vector_type(16)));

__device__ __forceinline__ f32x16 zero16() {
  f32x16 z;
#pragma unroll
  for (int i = 0; i < 16; ++i) z[i] = 0.f;
  return z;
}

// ---------------------------------------------------------------------------
// K0: zero G[b][128][128] and r[b][128] (ws is poisoned before each call)
// ---------------------------------------------------------------------------
__global__ __launch_bounds__(256) void k0_zero(float* __restrict__ p, int n)
{
  int i = blockIdx.x * 256 + threadIdx.x;
  if (i < n) p[i] = 0.f;
}

// ---------------------------------------------------------------------------
// K1: Gram G += x1 x1^T via LDS-staged tiles (1x HBM read), fp32 atomics into
//     G (131K addresses, L2-side -> cheap). Row-sums r likewise. 96 extra
//     blocks: fold wk'=we@wk(+bk'), wv'=wf@wv(+bv'), and wo -> bf16.
// ---------------------------------------------------------------------------
__global__ __launch_bounds__(256, 4) void k1_gram(
    const float* __restrict__ x1,
    const float* __restrict__ we, const float* __restrict__ wk,
    const float* __restrict__ bk, const float* __restrict__ be,
    const float* __restrict__ wf, const float* __restrict__ wv,
    const float* __restrict__ bv, const float* __restrict__ bfv,
    const float* __restrict__ wo,
    float* __restrict__ G, float* __restrict__ r,
    float* __restrict__ wkp, float* __restrict__ wvp,
    float* __restrict__ bkp, float* __restrict__ bvp,
    bf16* __restrict__ wobf)
{
  const int blk = blockIdx.x;
  const int tid = threadIdx.x;
  const int ngram = B_ * NCH_;   // 1024

  if (blk >= ngram) {
    const int wb = blk - ngram;  // 0..95
    if (wb < 64) {               // folded weights
      const float* wa  = (wb < 32) ? we : wf;
      const float* wb2 = (wb < 32) ? wk : wv;
      float* outw      = (wb < 32) ? wkp : wvp;
      const int idx = (wb & 31) * 256 + tid;   // 0..8191
      const int o = idx >> 7, d = idx & 127;
      float s = 0.f;
      for (int c = 0; c < 64; ++c) s += wa[o * 64 + c] * wb2[c * 128 + d];
      outw[idx] = s;
      if (tid < 64) {
        if (wb == 0) {
          float t = 0.f;
          for (int c = 0; c < 64; ++c) t += we[tid * 64 + c] * bk[c];
          bkp[tid] = t + be[tid];
        } else if (wb == 32) {
          float t = 0.f;
          for (int c = 0; c < 64; ++c) t += wf[tid * 64 + c] * bv[c];
          bvp[tid] = t + bfv[tid];
        }
      }
    } else {                     // wo -> bf16 (8192 elements over 32 blocks)
      const int idx = (wb - 64) * 256 + tid;
      wobf[idx] = (bf16)wo[idx];
    }
    return;
  }

  __shared__ bf16 x_s[128 * 72];   // [row][kcol], pad 64->72 (16B-aligned rows)

  const int b  = blk >> 7;
  const int ch = blk & (NCH_ - 1);
  const int t0 = ch * (T_ / NCH_);           // Tc = 256
  const int wave = tid >> 6, lane = tid & 63;
  const int lrow = lane & 31, lk = lane >> 5;
  const int qa = wave >> 1, qb = wave & 1;   // wave owns 64x64 quadrant

  const float* xb = x1 + (size_t)b * D_ * T_;

  f32x16 acc00 = zero16(), acc01 = zero16(), acc10 = zero16(), acc11 = zero16();
  float rsum = 0.f;

  const int scol = (tid & 15) * 4;           // staging col for this thread
  const int srow0 = tid >> 4;                // staging row base (0..15)

  const bf16* A0  = &x_s[(64 * qa + lrow) * 72 + 8 * lk];
  const bf16* A1  = A0 + 32 * 72;
  const bf16* Bb0 = &x_s[(64 * qb + lrow) * 72 + 8 * lk];
  const bf16* Bb1 = Bb0 + 32 * 72;

  for (int s = 0; s < 4; ++s) {              // 4 stages of 64 t-cols
    const int tb = t0 + s * 64;
    if (s) __syncthreads();                  // prev-stage reads done before overwrite
#pragma unroll
    for (int it = 0; it < 8; ++it) {
      const int row = it * 16 + srow0;
      f32x4 v = *(const f32x4*)(xb + (size_t)row * T_ + tb + scol);
      bf16x4 h;
#pragma unroll
      for (int j = 0; j < 4; ++j) h[j] = (bf16)v[j];
      *(bf16x4*)&x_s[row * 72 + scol] = h;
    }
    __syncthreads();
#pragma unroll
    for (int k = 0; k < 4; ++k) {
      bf16x8 fa0 = *(const bf16x8*)(A0 + 16 * k);
      bf16x8 fa1 = *(const bf16x8*)(A1 + 16 * k);
      bf16x8 fb0 = *(const bf16x8*)(Bb0 + 16 * k);
      bf16x8 fb1 = *(const bf16x8*)(Bb1 + 16 * k);
      bf16x8 own = qb ? fa1 : fa0;           // wave w sums rows 32w..32w+31
#pragma unroll
      for (int j = 0; j < 8; ++j) rsum += (float)own[j];
      acc00 = __builtin_amdgcn_mfma_f32_32x32x16_bf16(fa0, fb0, acc00, 0, 0, 0);
      acc01 = __builtin_amdgcn_mfma_f32_32x32x16_bf16(fa0, fb1, acc01, 0, 0, 0);
      acc10 = __builtin_amdgcn_mfma_f32_32x32x16_bf16(fa1, fb0, acc10, 0, 0, 0);
      acc11 = __builtin_amdgcn_mfma_f32_32x32x16_bf16(fa1, fb1, acc11, 0, 0, 0);
    }
  }

  float* gb = G + (size_t)b * 16384;
#pragma unroll
  for (int rr = 0; rr < 16; ++rr) {
    const int rloc = (rr & 3) + 8 * (rr >> 2) + 4 * lk;   // C/D row map (m74/m101)
    const int r0 = 64 * qa + rloc, r1 = 64 * qa + 32 + rloc;
    const int c0 = 64 * qb + lrow, c1 = 64 * qb + 32 + lrow;
    atomicAdd(&gb[r0 * 128 + c0], acc00[rr]);
    atomicAdd(&gb[r0 * 128 + c1], acc01[rr]);
    atomicAdd(&gb[r1 * 128 + c0], acc10[rr]);
    atomicAdd(&gb[r1 * 128 + c1], acc11[rr]);
  }
  float rtot = rsum + __shfl_xor(rsum, 32, 64);
  if (lk == 0) atomicAdd(&r[b * 128 + 32 * wave + lrow], rtot);
}

// ---------------------------------------------------------------------------
// K3: per (b, c): S[c,:] = wq_c G wk'^T + exact bias terms (via r),
//     P = softmax(S/8), att_w[c,:] = P @ wv' (bf16), att_b[c] = P @ bv'
// ---------------------------------------------------------------------------
__global__ __launch_bounds__(128) void k3_softmax(
    const float* __restrict__ wq, const float* __restrict__ bq,
    const float* __restrict__ G, const float* __restrict__ r,
    const float* __restrict__ wkp, const float* __restrict__ wvp,
    const float* __restrict__ bkp, const float* __restrict__ bvp,
    bf16* __restrict__ attw, float* __restrict__ attb)
{
  const int b = blockIdx.x >> 6, c = blockIdx.x & 63;
  const int tid = threadIdx.x;
  __shared__ float sM[128], sR[128], sQ[128], sP[64];
  __shared__ float sRed;

  const float* Gb = G + (size_t)b * 16384;
  const float* wqc = wq + c * 128;

  const float rv = r[b * 128 + tid];
  sR[tid] = rv;
  float m = 0.f;
  for (int j = 0; j < 128; ++j) m += wqc[j] * Gb[j * 128 + tid];
  sM[tid] = m;
  sQ[tid] = wqc[tid] * rv;
  __syncthreads();

  if (tid < 64) {
    float q2 = sQ[tid] + sQ[tid + 64];
#pragma unroll
    for (int off = 32; off; off >>= 1) q2 += __shfl_xor(q2, off, 64);
    if (tid == 0) sRed = q2;
  }
  __syncthreads();
  const float qr = sRed;
  const float bqc = bq[c];

  if (tid < 64) {
    const int k = tid;
    float s = 0.f, wkr = 0.f;
    for (int i = 0; i < 128; ++i) {
      const float w = wkp[k * 128 + i];
      s += sM[i] * w;
      wkr += sR[i] * w;
    }
    const float bk2 = bkp[k];
    float logit = (s + bqc * wkr + bk2 * qr + (float)T_ * bqc * bk2) * 0.125f;
    float mx = logit;
#pragma unroll
    for (int off = 32; off; off >>= 1) mx = fmaxf(mx, __shfl_xor(mx, off, 64));
    const float e = __expf(logit - mx);
    float sum = e;
#pragma unroll
    for (int off = 32; off; off >>= 1) sum += __shfl_xor(sum, off, 64);
    sP[k] = e / sum;
  }
  __syncthreads();

  {
    float aw = 0.f;
    for (int k = 0; k < 64; ++k) aw += sP[k] * wvp[k * 128 + tid];
    attw[((size_t)b * 64 + c) * 128 + tid] = (bf16)aw;
  }
  if (tid < 64) {
    float pb = sP[tid] * bvp[tid];
#pragma unroll
    for (int off = 32; off; off >>= 1) pb += __shfl_xor(pb, off, 64);
    if (tid == 0) attb[b * 64 + c] = pb;
  }
}

// ---------------------------------------------------------------------------
// K4: fused output, barrier-free main path. Per (b, 128-wide t-tile):
//   stage1 B-frags read DIRECTLY from global x1 (coalesced dword loads),
//   M1 = relu(attw@x + ab) -> small [t][c] LDS (pad 72; within-lane rows
//   only -> no barrier), stage2 out = wobf@m1 + bo, masked fp32 store.
// ---------------------------------------------------------------------------
__global__ __launch_bounds__(256, 4) void k4_out(
    const float* __restrict__ x1, const float* __restrict__ mask,
    const bf16* __restrict__ wobf, const float* __restrict__ bo,
    const bf16* __restrict__ attw, const float* __restrict__ attb,
    float* __restrict__ out)
{
  __shared__ bf16 m1[128 * 72];   // [t][c], pad 64->72
  __shared__ float bo_s[128];
  __shared__ float ab_s[64];

  const int b = blockIdx.x >> 8;           // 256 tiles per batch
  const int t0 = (blockIdx.x & 255) << 7;
  const int tid = threadIdx.x;
  const int wave = tid >> 6, lane = tid & 63;
  const int lrow = lane & 31, lk = lane >> 5;
  const int tcol = 32 * wave + lrow;

  if (tid < 128) bo_s[tid] = bo[tid];
  if (tid < 64) ab_s[tid] = attb[b * 64 + tid];
  __syncthreads();                          // only barrier (tiny staging)

  const float* xc = x1 + (size_t)b * D_ * T_ + t0 + tcol;   // column base
  const bf16* awb = attw + (size_t)b * 8192;

  // ---- stage 1: M1[c][t] = attw[c][d] * x[d][t]
  f32x16 p0 = zero16(), p1 = zero16();
#pragma unroll
  for (int k0 = 0; k0 < 8; ++k0) {
    bf16x8 a0 = *(const bf16x8*)(awb + (size_t)lrow * 128 + 16 * k0 + 8 * lk);
    bf16x8 a1 = *(const bf16x8*)(awb + (size_t)(32 + lrow) * 128 + 16 * k0 + 8 * lk);
    bf16x8 bx;
#pragma unroll
    for (int j = 0; j < 8; ++j)
      bx[j] = (bf16)xc[(size_t)(16 * k0 + 8 * lk + j) * T_];
    p0 = __builtin_amdgcn_mfma_f32_32x32x16_bf16(a0, bx, p0, 0, 0, 0);
    p1 = __builtin_amdgcn_mfma_f32_32x32x16_bf16(a1, bx, p1, 0, 0, 0);
  }
  bf16* mrow = &m1[tcol * 72];              // this lane's own t-row
#pragma unroll
  for (int rr = 0; rr < 16; ++rr) {
    const int row = (rr & 3) + 8 * (rr >> 2) + 4 * lk;
    mrow[row]      = (bf16)fmaxf(p0[rr] + ab_s[row], 0.f);
    mrow[32 + row] = (bf16)fmaxf(p1[rr] + ab_s[32 + row], 0.f);
  }

  // ---- stage 2: out[d][t] = wobf[d][c] * m1[c][t] (own row, no barrier)
  f32x16 q0 = zero16(), q1 = zero16(), q2 = zero16(), q3 = zero16();
#pragma unroll
  for (int k0 = 0; k0 < 4; ++k0) {
    bf16x8 bm = *(const bf16x8*)(mrow + 16 * k0 + 8 * lk);
    bf16x8 w0 = *(const bf16x8*)(wobf + (size_t)(lrow) * 64 + 16 * k0 + 8 * lk);
    bf16x8 w1 = *(const bf16x8*)(wobf + (size_t)(32 + lrow) * 64 + 16 * k0 + 8 * lk);
    bf16x8 w2 = *(const bf16x8*)(wobf + (size_t)(64 + lrow) * 64 + 16 * k0 + 8 * lk);
    bf16x8 w3 = *(const bf16x8*)(wobf + (size_t)(96 + lrow) * 64 + 16 * k0 + 8 * lk);
    q0 = __builtin_amdgcn_mfma_f32_32x32x16_bf16(w0, bm, q0, 0, 0, 0);
    q1 = __builtin_amdgcn_mfma_f32_32x32x16_bf16(w1, bm, q1, 0, 0, 0);
    q2 = __builtin_amdgcn_mfma_f32_32x32x16_bf16(w2, bm, q2, 0, 0, 0);
    q3 = __builtin_amdgcn_mfma_f32_32x32x16_bf16(w3, bm, q3, 0, 0, 0);
  }

  const float mv = mask[(size_t)b * T_ + t0 + tcol];
  float* ob = out + (size_t)b * D_ * T_ + t0 + tcol;
#pragma unroll
  for (int rr = 0; rr < 16; ++rr) {
    const int row = (rr & 3) + 8 * (rr >> 2) + 4 * lk;
    ob[(size_t)(row) * T_]      = (q0[rr] + bo_s[row]) * mv;
    ob[(size_t)(32 + row) * T_] = (q1[rr] + bo_s[32 + row]) * mv;
    ob[(size_t)(64 + row) * T_] = (q2[rr] + bo_s[64 + row]) * mv;
    ob[(size_t)(96 + row) * T_] = (q3[rr] + bo_s[96 + row]) * mv;
  }
}

// ---------------------------------------------------------------------------
// Workspace: G[512K] r[4K] wkp[32K] wvp[32K] bkp/bvp/attb small, attw 16K(bf16),
// wobf 16K(bf16) -> ~0.65 MB total. Single tier.
// ---------------------------------------------------------------------------
extern "C" void kernel_launch(void* const* d_in, const int* in_sizes, int n_in,
                              void* d_out, int out_size, void* d_ws, size_t ws_size,
                              hipStream_t stream)
{
  const float* x1   = (const float*)d_in[0];
  // d_in[1] = x2 (unused in encoder stage)
  const float* mask = (const float*)d_in[2];
  const float* wq   = (const float*)d_in[3];
  const float* bq   = (const float*)d_in[4];
  const float* wk   = (const float*)d_in[5];
  const float* bk   = (const float*)d_in[6];
  const float* wv   = (const float*)d_in[7];
  const float* bv   = (const float*)d_in[8];
  const float* we   = (const float*)d_in[9];
  const float* be   = (const float*)d_in[10];
  const float* wf   = (const float*)d_in[11];
  const float* bfv  = (const float*)d_in[12];
  const float* wo   = (const float*)d_in[13];
  const float* bo   = (const float*)d_in[14];
  float* out = (float*)d_out;

  char* base = (char*)d_ws;
  size_t off = 0;
  float* G    = (float*)(base + off); off += (size_t)B_ * 16384 * 4;
  float* r    = (float*)(base + off); off += (size_t)B_ * 128 * 4;
  float* wkp  = (float*)(base + off); off += 8192 * 4;
  float* wvp  = (float*)(base + off); off += 8192 * 4;
  float* bkp  = (float*)(base + off); off += 64 * 4;
  float* bvp  = (float*)(base + off); off += 64 * 4;
  float* attb = (float*)(base + off); off += (size_t)B_ * 64 * 4;
  bf16* attw  = (bf16*)(base + off);  off += (size_t)B_ * 64 * 128 * 2;
  bf16* wobf  = (bf16*)(base + off);  off += 8192 * 2;

  const int nzero = B_ * 16384 + B_ * 128;   // G + r contiguous
  k0_zero<<<(nzero + 255) / 256, 256, 0, stream>>>(G, nzero);
  k1_gram<<<B_ * NCH_ + 96, 256, 0, stream>>>(
      x1, we, wk, bk, be, wf, wv, bv, bfv, wo,
      G, r, wkp, wvp, bkp, bvp, wobf);
  k3_softmax<<<B_ * 64, 128, 0, stream>>>(wq, bq, G, r, wkp, wvp, bkp, bvp, attw, attb);
  k4_out<<<B_ * (T_ / 128), 256, 0, stream>>>(x1, mask, wobf, bo, attw, attb, out);
}